// Round 1
// baseline (932.817 us; speedup 1.0000x reference)
//
#include <hip/hip_runtime.h>
#include <cstdint>
#include <cstddef>
#include <math.h>

// Problem constants (from reference)
#define NNODES 20000
#define NEDGES 320000
#define TDIM   8
#define CDIM   32
#define RROWS  (NNODES * TDIM)           // 160000 rows of 32 floats
#define NELEM  (RROWS * CDIM)            // 5,120,000 elements per [N,T,C] tensor

// ---------------------------------------------------------------------------
// Fused linear kernel: h = in @ W ; hu = h @ U.  One row (32 floats) per thread.
// Weights staged in LDS (2 x 4KB).
// ---------------------------------------------------------------------------
__global__ __launch_bounds__(256) void linear2_kernel(
    const float* __restrict__ in,   // [RROWS, 32]
    const float* __restrict__ W,    // [32, 32]
    const float* __restrict__ U,    // [32, 32]
    float* __restrict__ h,          // [RROWS, 32]
    float* __restrict__ hu)         // [RROWS, 32]
{
    __shared__ float sW[CDIM][CDIM];
    __shared__ float sU[CDIM][CDIM];
    int tid = threadIdx.x;
#pragma unroll
    for (int i = 0; i < 4; ++i) {
        int idx = tid + i * 256;
        ((float*)sW)[idx] = W[idx];
        ((float*)sU)[idx] = U[idx];
    }
    __syncthreads();

    int row = blockIdx.x * 256 + tid;
    if (row >= RROWS) return;

    const float* xr = in + (size_t)row * CDIM;
    float x[CDIM];
#pragma unroll
    for (int k = 0; k < CDIM / 4; ++k) {
        float4 v = ((const float4*)xr)[k];
        x[4 * k + 0] = v.x; x[4 * k + 1] = v.y;
        x[4 * k + 2] = v.z; x[4 * k + 3] = v.w;
    }

    float hr[CDIM];
#pragma unroll
    for (int c = 0; c < CDIM; ++c) {
        float acc = 0.f;
#pragma unroll
        for (int k = 0; k < CDIM; ++k) acc += x[k] * sW[k][c];
        hr[c] = acc;
    }

    float* hrow = h + (size_t)row * CDIM;
#pragma unroll
    for (int k = 0; k < CDIM / 4; ++k) {
        ((float4*)hrow)[k] = make_float4(hr[4 * k], hr[4 * k + 1],
                                         hr[4 * k + 2], hr[4 * k + 3]);
    }

    // reuse x[] as hu accumulator
#pragma unroll
    for (int c = 0; c < CDIM; ++c) {
        float acc = 0.f;
#pragma unroll
        for (int k = 0; k < CDIM; ++k) acc += hr[k] * sU[k][c];
        x[c] = acc;
    }

    float* hurow = hu + (size_t)row * CDIM;
#pragma unroll
    for (int k = 0; k < CDIM / 4; ++k) {
        ((float4*)hurow)[k] = make_float4(x[4 * k], x[4 * k + 1],
                                          x[4 * k + 2], x[4 * k + 3]);
    }
}

// ---------------------------------------------------------------------------
// Fill agg buffer with -inf (segment_max identity).
// ---------------------------------------------------------------------------
__global__ __launch_bounds__(256) void init_agg_kernel(float4* __restrict__ agg)
{
    int i = blockIdx.x * 256 + threadIdx.x;
    if (i < NELEM / 4) {
        agg[i] = make_float4(-INFINITY, -INFINITY, -INFINITY, -INFINITY);
    }
}

// ---------------------------------------------------------------------------
// Edge kernel: one 32-lane group per (edge, tau).  Lane c owns channel c.
// gate = sigmoid(<hu[src,tau,:], hu[tgt,tau,:]>); atomic float-max of
// hu[src,tau,c]*gate into agg[tgt,tau,c].
// Float atomic-max via signed-int max (v>=0) / unsigned-int min (v<0):
// monotone bit encodings make this exact; max is order-independent ->
// deterministic output.
// ---------------------------------------------------------------------------
__global__ __launch_bounds__(256) void edge_kernel(
    const int* __restrict__ ei,     // [2, NEDGES]
    const float* __restrict__ hu,   // [RROWS, 32]
    float* __restrict__ agg)        // [RROWS, 32]
{
    long long gid = (long long)blockIdx.x * 256 + threadIdx.x;
    int group = (int)(gid >> 5);          // e*8 + tau
    int c = (int)(gid & 31);
    if (group >= NEDGES * TDIM) return;
    int e = group >> 3;
    int tau = group & 7;

    int s = ei[e];            // src
    int t = ei[NEDGES + e];   // tgt

    const float* hs = hu + ((size_t)s * TDIM + tau) * CDIM;
    const float* ht = hu + ((size_t)t * TDIM + tau) * CDIM;
    float a = hs[c];          // x_j (src) channel c
    float b = ht[c];          // x_i (tgt) channel c
    float p = a * b;
    // 32-lane butterfly sum (masks < 32 stay within each wave half)
#pragma unroll
    for (int m = 16; m >= 1; m >>= 1) p += __shfl_xor(p, m);
    float gate = 1.f / (1.f + __expf(-p));
    float v = a * gate;

    float* addr = agg + ((size_t)t * TDIM + tau) * CDIM + c;
    if (v >= 0.f) atomicMax((int*)addr, __float_as_int(v));
    else          atomicMin((unsigned int*)addr, __float_as_uint(v));
}

// ---------------------------------------------------------------------------
// out = leaky_relu(h + (isfinite(agg) ? agg : 0), 0.01)
// ---------------------------------------------------------------------------
__global__ __launch_bounds__(256) void finish_kernel(
    const float* __restrict__ h,
    const float* __restrict__ agg,
    float* __restrict__ out)
{
    int i = blockIdx.x * 256 + threadIdx.x;
    if (i >= NELEM) return;
    float a = agg[i];
    if (!isfinite(a)) a = 0.f;
    float v = h[i] + a;
    out[i] = (v >= 0.f) ? v : 0.01f * v;
}

// ---------------------------------------------------------------------------
// Orchestration.
// Workspace layout: A = ws[0 .. NELEM), B = ws[NELEM .. 2*NELEM)  (41 MB).
// Layer 1: h1->A, hu1->B, agg1->d_out, c1=leaky(h1+agg1)->A (in place)
// Layer 2: h2->B, hu2->d_out, agg2->A, out=leaky(h2+agg2)->d_out
// ---------------------------------------------------------------------------
extern "C" void kernel_launch(void* const* d_in, const int* in_sizes, int n_in,
                              void* d_out, int out_size, void* d_ws, size_t ws_size,
                              hipStream_t stream)
{
    const float* X   = (const float*)d_in[0];
    const int*   ei  = (const int*)  d_in[1];
    // d_in[2] = edge_attr, d_in[4] = We1, d_in[7] = We2: dead code in reference
    const float* Wn1 = (const float*)d_in[3];
    const float* u1  = (const float*)d_in[5];
    const float* Wn2 = (const float*)d_in[6];
    const float* u2  = (const float*)d_in[8];

    float* out = (float*)d_out;
    float* A = (float*)d_ws;
    float* B = A + (size_t)NELEM;

    const int rowBlocks  = (RROWS + 255) / 256;          // 625
    const int initBlocks = (NELEM / 4 + 255) / 256;      // 5000
    const int edgeBlocks = (int)(((long long)NEDGES * TDIM * CDIM + 255) / 256); // 320000
    const int elemBlocks = (NELEM + 255) / 256;          // 20000

    // ---- layer 1 ----
    linear2_kernel<<<rowBlocks, 256, 0, stream>>>(X, Wn1, u1, A, B);
    init_agg_kernel<<<initBlocks, 256, 0, stream>>>((float4*)out);
    edge_kernel<<<edgeBlocks, 256, 0, stream>>>(ei, B, out);
    finish_kernel<<<elemBlocks, 256, 0, stream>>>(A, out, A);   // c1 -> A

    // ---- layer 2 ----
    linear2_kernel<<<rowBlocks, 256, 0, stream>>>(A, Wn2, u2, B, out); // h2->B, hu2->out
    init_agg_kernel<<<initBlocks, 256, 0, stream>>>((float4*)A);
    edge_kernel<<<edgeBlocks, 256, 0, stream>>>(ei, out, A);
    finish_kernel<<<elemBlocks, 256, 0, stream>>>(B, A, out);   // final -> d_out
}

// Round 2
// 342.139 us; speedup vs baseline: 2.7264x; 2.7264x over previous
//
#include <hip/hip_runtime.h>
#include <cstdint>
#include <cstddef>
#include <math.h>

// Problem constants (from reference)
#define NNODES 20000
#define NEDGES 320000
#define TDIM   8
#define CDIM   32
#define RROWS  (NNODES * TDIM)           // 160000 rows of 32 floats
#define NELEM  (RROWS * CDIM)            // 5,120,000 elements per [N,T,C] tensor
#define ROWBLK (TDIM * CDIM)             // 256 floats per node (all tau, all ch)

// ---------------------------------------------------------------------------
// Fused linear kernel: h = in @ W ; hu = h @ U.  One row (32 floats) per thread.
// Weights staged in LDS.  NOTE: `in` and `hu` may alias (per-thread row
// read-before-write), so no __restrict__ on them.
// ---------------------------------------------------------------------------
__global__ __launch_bounds__(256) void linear2_kernel(
    const float* in,                // [RROWS, 32]
    const float* __restrict__ W,    // [32, 32]
    const float* __restrict__ U,    // [32, 32]
    float* __restrict__ h,          // [RROWS, 32]
    float* hu)                      // [RROWS, 32]
{
    __shared__ float sW[CDIM][CDIM];
    __shared__ float sU[CDIM][CDIM];
    int tid = threadIdx.x;
#pragma unroll
    for (int i = 0; i < 4; ++i) {
        int idx = tid + i * 256;
        ((float*)sW)[idx] = W[idx];
        ((float*)sU)[idx] = U[idx];
    }
    __syncthreads();

    int row = blockIdx.x * 256 + tid;
    if (row >= RROWS) return;

    const float* xr = in + (size_t)row * CDIM;
    float x[CDIM];
#pragma unroll
    for (int k = 0; k < CDIM / 4; ++k) {
        float4 v = ((const float4*)xr)[k];
        x[4 * k + 0] = v.x; x[4 * k + 1] = v.y;
        x[4 * k + 2] = v.z; x[4 * k + 3] = v.w;
    }

    float hr[CDIM];
#pragma unroll
    for (int c = 0; c < CDIM; ++c) {
        float acc = 0.f;
#pragma unroll
        for (int k = 0; k < CDIM; ++k) acc += x[k] * sW[k][c];
        hr[c] = acc;
    }

    float* hrow = h + (size_t)row * CDIM;
#pragma unroll
    for (int k = 0; k < CDIM / 4; ++k) {
        ((float4*)hrow)[k] = make_float4(hr[4 * k], hr[4 * k + 1],
                                         hr[4 * k + 2], hr[4 * k + 3]);
    }

    // reuse x[] as hu accumulator
#pragma unroll
    for (int c = 0; c < CDIM; ++c) {
        float acc = 0.f;
#pragma unroll
        for (int k = 0; k < CDIM; ++k) acc += hr[k] * sU[k][c];
        x[c] = acc;
    }

    float* hurow = hu + (size_t)row * CDIM;
#pragma unroll
    for (int k = 0; k < CDIM / 4; ++k) {
        ((float4*)hurow)[k] = make_float4(x[4 * k], x[4 * k + 1],
                                          x[4 * k + 2], x[4 * k + 3]);
    }
}

// ---------------------------------------------------------------------------
// CSR build: counts -> scan -> scatter.  Edge topology is shared by both
// layers, so this runs once per launch.
// ---------------------------------------------------------------------------
__global__ __launch_bounds__(256) void zero_counts_kernel(int* __restrict__ counts)
{
    int i = blockIdx.x * 256 + threadIdx.x;
    if (i < NNODES) counts[i] = 0;
}

__global__ __launch_bounds__(256) void hist_kernel(
    const int* __restrict__ ei, int* __restrict__ counts)
{
    int e = blockIdx.x * 256 + threadIdx.x;
    if (e < NEDGES) atomicAdd(&counts[ei[NEDGES + e]], 1);
}

// single-block exclusive scan of counts[NNODES] -> offsets[NNODES+1], cursor
__global__ __launch_bounds__(1024) void scan_kernel(
    const int* __restrict__ counts,
    int* __restrict__ offsets,
    int* __restrict__ cursor)
{
    __shared__ int sdata[1024];
    int running = 0;
    for (int base = 0; base < NNODES; base += 1024) {
        int i = base + threadIdx.x;
        int v = (i < NNODES) ? counts[i] : 0;
        __syncthreads();               // protect sdata from prev-chunk readers
        sdata[threadIdx.x] = v;
        __syncthreads();
#pragma unroll
        for (int off = 1; off < 1024; off <<= 1) {
            int t = (threadIdx.x >= off) ? sdata[threadIdx.x - off] : 0;
            __syncthreads();
            sdata[threadIdx.x] += t;
            __syncthreads();
        }
        int incl = sdata[threadIdx.x];
        if (i < NNODES) {
            int excl = running + incl - v;
            offsets[i] = excl;
            cursor[i]  = excl;
        }
        running += sdata[1023];        // block total (broadcast read)
    }
    if (threadIdx.x == 0) offsets[NNODES] = running;
}

__global__ __launch_bounds__(256) void scatter_kernel(
    const int* __restrict__ ei,
    int* __restrict__ cursor,
    int* __restrict__ csr_src)
{
    int e = blockIdx.x * 256 + threadIdx.x;
    if (e < NEDGES) {
        int t = ei[NEDGES + e];
        int pos = atomicAdd(&cursor[t], 1);
        csr_src[pos] = ei[e];
    }
}

// ---------------------------------------------------------------------------
// Aggregation kernel: one block per target node; thread = (tau, c).
// Iterates the node's in-edges from CSR, computes gate = sigmoid(<x_i,x_j>)
// per (edge,tau) via 32-lane butterfly, running max in registers, then writes
// out = leaky_relu(h + agg, 0.01) once.  No atomics, no -inf init pass.
// `h` and `out` may alias (per-thread read-before-write).
// ---------------------------------------------------------------------------
__global__ __launch_bounds__(256) void agg_kernel(
    const int* __restrict__ offsets,
    const int* __restrict__ csr_src,
    const float* __restrict__ hu,   // gather source [RROWS,32]
    const float* h,                 // [RROWS,32]
    float* out)                     // [RROWS,32]
{
    int n = blockIdx.x;
    int tid = threadIdx.x;          // tau*32 + c
    size_t base = (size_t)n * ROWBLK + tid;

    float b = hu[base];             // x_i channel value for this (tau,c)
    int k0 = offsets[n];
    int k1 = offsets[n + 1];

    float m = -INFINITY;
    if (k0 < k1) {
        int s = csr_src[k0];
        float a = hu[(size_t)s * ROWBLK + tid];
        for (int k = k0 + 1; ; ++k) {
            bool more = (k < k1);
            int sn = 0; float an = 0.f;
            if (more) {
                sn = csr_src[k];
                an = hu[(size_t)sn * ROWBLK + tid];   // prefetch next row
            }
            float p = a * b;
#pragma unroll
            for (int msk = 16; msk >= 1; msk >>= 1) p += __shfl_xor(p, msk);
            float gate = 1.f / (1.f + __expf(-p));
            m = fmaxf(m, a * gate);
            if (!more) break;
            a = an;
        }
    }
    float aval = (k1 > k0) ? m : 0.f;   // empty segment -> 0 (PyG fill)
    float v = h[base] + aval;
    out[base] = (v >= 0.f) ? v : 0.01f * v;
}

// ---------------------------------------------------------------------------
// Orchestration.
// ws layout: [counts N][offsets N+1][cursor N][csr E][pad][A NELEM]  (~22 MB)
// Layer 1: linear2(X)->h1=A, hu1=d_out;  agg(hu=d_out,h=A)->c1=A (in place)
// Layer 2: linear2(A)->h2=d_out, hu2=A (in place); agg(hu=A,h=d_out)->d_out
// ---------------------------------------------------------------------------
extern "C" void kernel_launch(void* const* d_in, const int* in_sizes, int n_in,
                              void* d_out, int out_size, void* d_ws, size_t ws_size,
                              hipStream_t stream)
{
    const float* X   = (const float*)d_in[0];
    const int*   ei  = (const int*)  d_in[1];
    // d_in[2]=edge_attr, d_in[4]=We1, d_in[7]=We2: dead code in reference
    const float* Wn1 = (const float*)d_in[3];
    const float* u1  = (const float*)d_in[5];
    const float* Wn2 = (const float*)d_in[6];
    const float* u2  = (const float*)d_in[8];

    float* out = (float*)d_out;

    int* counts  = (int*)d_ws;
    int* offsets = counts + NNODES;          // NNODES+1
    int* cursor  = offsets + NNODES + 1;
    int* csr     = cursor + NNODES;          // NEDGES
    float* A = (float*)(((uintptr_t)(csr + NEDGES) + 255) & ~(uintptr_t)255);

    const int rowBlocks  = (RROWS + 255) / 256;    // 625
    const int edgeBlocks = (NEDGES + 255) / 256;   // 1250
    const int nodeBlocks = (NNODES + 255) / 256;   // 79

    // ---- CSR build (shared by both layers) ----
    zero_counts_kernel<<<nodeBlocks, 256, 0, stream>>>(counts);
    hist_kernel<<<edgeBlocks, 256, 0, stream>>>(ei, counts);
    scan_kernel<<<1, 1024, 0, stream>>>(counts, offsets, cursor);
    scatter_kernel<<<edgeBlocks, 256, 0, stream>>>(ei, cursor, csr);

    // ---- layer 1 ----
    linear2_kernel<<<rowBlocks, 256, 0, stream>>>(X, Wn1, u1, A, out);
    agg_kernel<<<NNODES, 256, 0, stream>>>(offsets, csr, out, A, A);

    // ---- layer 2 ----
    linear2_kernel<<<rowBlocks, 256, 0, stream>>>(A, Wn2, u2, out, A);
    agg_kernel<<<NNODES, 256, 0, stream>>>(offsets, csr, A, out, out);
}

// Round 3
// 271.815 us; speedup vs baseline: 3.4318x; 1.2587x over previous
//
#include <hip/hip_runtime.h>
#include <cstdint>
#include <cstddef>
#include <math.h>

// Problem constants (from reference)
#define NNODES 20000
#define NEDGES 320000
#define TDIM   8
#define CDIM   32
#define RROWS  (NNODES * TDIM)           // 160000 rows of 32 floats
#define NELEM  (RROWS * CDIM)            // 5,120,000 elements per [N,T,C] tensor
#define ROWBLK (TDIM * CDIM)             // 256 floats per node (all tau, all ch)

// ---------------------------------------------------------------------------
// Fused linear kernel: h = in @ W ; hu = h @ U.  One row (32 floats) per thread.
// Weights staged in LDS.  NOTE: `in` and `hu` may alias (per-thread row
// read-before-write), so no __restrict__ on them.
// ---------------------------------------------------------------------------
__global__ __launch_bounds__(256) void linear2_kernel(
    const float* in,                // [RROWS, 32]
    const float* __restrict__ W,    // [32, 32]
    const float* __restrict__ U,    // [32, 32]
    float* __restrict__ h,          // [RROWS, 32]
    float* hu)                      // [RROWS, 32]
{
    __shared__ float sW[CDIM][CDIM];
    __shared__ float sU[CDIM][CDIM];
    int tid = threadIdx.x;
#pragma unroll
    for (int i = 0; i < 4; ++i) {
        int idx = tid + i * 256;
        ((float*)sW)[idx] = W[idx];
        ((float*)sU)[idx] = U[idx];
    }
    __syncthreads();

    int row = blockIdx.x * 256 + tid;
    if (row >= RROWS) return;

    const float* xr = in + (size_t)row * CDIM;
    float x[CDIM];
#pragma unroll
    for (int k = 0; k < CDIM / 4; ++k) {
        float4 v = ((const float4*)xr)[k];
        x[4 * k + 0] = v.x; x[4 * k + 1] = v.y;
        x[4 * k + 2] = v.z; x[4 * k + 3] = v.w;
    }

    float hr[CDIM];
#pragma unroll
    for (int c = 0; c < CDIM; ++c) {
        float acc = 0.f;
#pragma unroll
        for (int k = 0; k < CDIM; ++k) acc += x[k] * sW[k][c];
        hr[c] = acc;
    }

    float* hrow = h + (size_t)row * CDIM;
#pragma unroll
    for (int k = 0; k < CDIM / 4; ++k) {
        ((float4*)hrow)[k] = make_float4(hr[4 * k], hr[4 * k + 1],
                                         hr[4 * k + 2], hr[4 * k + 3]);
    }

    // reuse x[] as hu accumulator
#pragma unroll
    for (int c = 0; c < CDIM; ++c) {
        float acc = 0.f;
#pragma unroll
        for (int k = 0; k < CDIM; ++k) acc += hr[k] * sU[k][c];
        x[c] = acc;
    }

    float* hurow = hu + (size_t)row * CDIM;
#pragma unroll
    for (int k = 0; k < CDIM / 4; ++k) {
        ((float4*)hurow)[k] = make_float4(x[4 * k], x[4 * k + 1],
                                          x[4 * k + 2], x[4 * k + 3]);
    }
}

// ---------------------------------------------------------------------------
// CSR build: counts -> scan -> scatter.  Runs once per launch (topology is
// shared by both layers).
// ---------------------------------------------------------------------------
__global__ __launch_bounds__(256) void zero_counts_kernel(int* __restrict__ counts)
{
    int i = blockIdx.x * 256 + threadIdx.x;
    if (i < NNODES) counts[i] = 0;
}

__global__ __launch_bounds__(256) void hist_kernel(
    const int* __restrict__ ei, int* __restrict__ counts)
{
    int e = blockIdx.x * 256 + threadIdx.x;
    if (e < NEDGES) atomicAdd(&counts[ei[NEDGES + e]], 1);
}

// single-block exclusive scan of counts[NNODES] -> offsets[NNODES+1], cursor
__global__ __launch_bounds__(1024) void scan_kernel(
    const int* __restrict__ counts,
    int* __restrict__ offsets,
    int* __restrict__ cursor)
{
    __shared__ int sdata[1024];
    int running = 0;
    for (int base = 0; base < NNODES; base += 1024) {
        int i = base + threadIdx.x;
        int v = (i < NNODES) ? counts[i] : 0;
        __syncthreads();               // protect sdata from prev-chunk readers
        sdata[threadIdx.x] = v;
        __syncthreads();
#pragma unroll
        for (int off = 1; off < 1024; off <<= 1) {
            int t = (threadIdx.x >= off) ? sdata[threadIdx.x - off] : 0;
            __syncthreads();
            sdata[threadIdx.x] += t;
            __syncthreads();
        }
        int incl = sdata[threadIdx.x];
        if (i < NNODES) {
            int excl = running + incl - v;
            offsets[i] = excl;
            cursor[i]  = excl;
        }
        running += sdata[1023];        // block total (broadcast read)
    }
    if (threadIdx.x == 0) offsets[NNODES] = running;
}

__global__ __launch_bounds__(256) void scatter_kernel(
    const int* __restrict__ ei,
    int* __restrict__ cursor,
    int* __restrict__ csr_src)
{
    int e = blockIdx.x * 256 + threadIdx.x;
    if (e < NEDGES) {
        int t = ei[NEDGES + e];
        int pos = atomicAdd(&cursor[t], 1);
        csr_src[pos] = ei[e];
    }
}

// ---------------------------------------------------------------------------
// Aggregation kernel: one block per target node; thread = (tau, c).
// Edge loop unrolled by 4: 4 independent gathers + 4 independent butterfly
// reduction chains in flight (attacks serial shfl-chain + gather latency).
// Writes out = leaky_relu(h + agg, 0.01) once.  `h`/`out` may alias.
// ---------------------------------------------------------------------------
__global__ __launch_bounds__(256) void agg_kernel(
    const int* __restrict__ offsets,
    const int* __restrict__ csr_src,
    const float* __restrict__ hu,   // gather source [RROWS,32]
    const float* h,                 // [RROWS,32]
    float* out)                     // [RROWS,32]
{
    int n = blockIdx.x;
    int tid = threadIdx.x;          // tau*32 + c
    size_t base = (size_t)n * ROWBLK + tid;

    float b = hu[base];             // x_i value for this (tau,c)
    int k0 = offsets[n];
    int k1 = offsets[n + 1];

    float m = -INFINITY;
    int k = k0;

    // main unrolled-by-4 loop: 4 rows + 4 butterflies in flight
    for (; k + 4 <= k1; k += 4) {
        int s0 = csr_src[k + 0];
        int s1 = csr_src[k + 1];
        int s2 = csr_src[k + 2];
        int s3 = csr_src[k + 3];
        float a0 = hu[(size_t)s0 * ROWBLK + tid];
        float a1 = hu[(size_t)s1 * ROWBLK + tid];
        float a2 = hu[(size_t)s2 * ROWBLK + tid];
        float a3 = hu[(size_t)s3 * ROWBLK + tid];
        float p0 = a0 * b, p1 = a1 * b, p2 = a2 * b, p3 = a3 * b;
#pragma unroll
        for (int msk = 16; msk >= 1; msk >>= 1) {
            p0 += __shfl_xor(p0, msk);
            p1 += __shfl_xor(p1, msk);
            p2 += __shfl_xor(p2, msk);
            p3 += __shfl_xor(p3, msk);
        }
        float g0 = a0 / (1.f + __expf(-p0));
        float g1 = a1 / (1.f + __expf(-p1));
        float g2 = a2 / (1.f + __expf(-p2));
        float g3 = a3 / (1.f + __expf(-p3));
        m = fmaxf(fmaxf(fmaxf(m, g0), fmaxf(g1, g2)), g3);
    }
    // tail
    for (; k < k1; ++k) {
        int s = csr_src[k];
        float a = hu[(size_t)s * ROWBLK + tid];
        float p = a * b;
#pragma unroll
        for (int msk = 16; msk >= 1; msk >>= 1) p += __shfl_xor(p, msk);
        m = fmaxf(m, a / (1.f + __expf(-p)));
    }

    float aval = (k1 > k0) ? m : 0.f;   // empty segment -> 0 (PyG fill)
    float v = h[base] + aval;
    out[base] = (v >= 0.f) ? v : 0.01f * v;
}

// ---------------------------------------------------------------------------
// Orchestration.
// ws layout: [counts N][offsets N+1][cursor N][csr E][pad][A NELEM]  (~22 MB)
// Layer 1: linear2(X)->h1=A, hu1=d_out;  agg(hu=d_out,h=A)->c1=A (in place)
// Layer 2: linear2(A)->h2=d_out, hu2=A (in place); agg(hu=A,h=d_out)->d_out
// ---------------------------------------------------------------------------
extern "C" void kernel_launch(void* const* d_in, const int* in_sizes, int n_in,
                              void* d_out, int out_size, void* d_ws, size_t ws_size,
                              hipStream_t stream)
{
    const float* X   = (const float*)d_in[0];
    const int*   ei  = (const int*)  d_in[1];
    // d_in[2]=edge_attr, d_in[4]=We1, d_in[7]=We2: dead code in reference
    const float* Wn1 = (const float*)d_in[3];
    const float* u1  = (const float*)d_in[5];
    const float* Wn2 = (const float*)d_in[6];
    const float* u2  = (const float*)d_in[8];

    float* out = (float*)d_out;

    int* counts  = (int*)d_ws;
    int* offsets = counts + NNODES;          // NNODES+1
    int* cursor  = offsets + NNODES + 1;
    int* csr     = cursor + NNODES;          // NEDGES
    float* A = (float*)(((uintptr_t)(csr + NEDGES) + 255) & ~(uintptr_t)255);

    const int rowBlocks  = (RROWS + 255) / 256;    // 625
    const int edgeBlocks = (NEDGES + 255) / 256;   // 1250
    const int nodeBlocks = (NNODES + 255) / 256;   // 79

    // ---- CSR build (shared by both layers) ----
    zero_counts_kernel<<<nodeBlocks, 256, 0, stream>>>(counts);
    hist_kernel<<<edgeBlocks, 256, 0, stream>>>(ei, counts);
    scan_kernel<<<1, 1024, 0, stream>>>(counts, offsets, cursor);
    scatter_kernel<<<edgeBlocks, 256, 0, stream>>>(ei, cursor, csr);

    // ---- layer 1 ----
    linear2_kernel<<<rowBlocks, 256, 0, stream>>>(X, Wn1, u1, A, out);
    agg_kernel<<<NNODES, 256, 0, stream>>>(offsets, csr, out, A, A);

    // ---- layer 2 ----
    linear2_kernel<<<rowBlocks, 256, 0, stream>>>(A, Wn2, u2, out, A);
    agg_kernel<<<NNODES, 256, 0, stream>>>(offsets, csr, A, out, out);
}

// Round 4
// 192.000 us; speedup vs baseline: 4.8584x; 1.4157x over previous
//
#include <hip/hip_runtime.h>
#include <cstdint>
#include <cstddef>
#include <math.h>

// Problem constants (from reference)
#define NNODES 20000
#define NEDGES 320000
#define TDIM   8
#define CDIM   32
#define RROWS  (NNODES * TDIM)           // 160000 rows of 32 floats
#define NELEM  (RROWS * CDIM)            // 5,120,000 elements per [N,T,C] tensor
#define ROWBLK (TDIM * CDIM)             // 256 floats per node (all tau, all ch)

static __device__ __forceinline__ float4 fmax4(float4 a, float4 b) {
    return make_float4(fmaxf(a.x, b.x), fmaxf(a.y, b.y),
                       fmaxf(a.z, b.z), fmaxf(a.w, b.w));
}

// ---------------------------------------------------------------------------
// Fused linear kernel: h = in @ W ; hu = h @ U.  One row (32 floats) per thread.
// Weights staged in LDS.  `in`/`hu` may alias (per-thread row RAW), so no
// __restrict__ on them.
// ---------------------------------------------------------------------------
__global__ __launch_bounds__(256) void linear2_kernel(
    const float* in,                // [RROWS, 32]
    const float* __restrict__ W,    // [32, 32]
    const float* __restrict__ U,    // [32, 32]
    float* __restrict__ h,          // [RROWS, 32]
    float* hu)                      // [RROWS, 32]
{
    __shared__ float sW[CDIM][CDIM];
    __shared__ float sU[CDIM][CDIM];
    int tid = threadIdx.x;
#pragma unroll
    for (int i = 0; i < 4; ++i) {
        int idx = tid + i * 256;
        ((float*)sW)[idx] = W[idx];
        ((float*)sU)[idx] = U[idx];
    }
    __syncthreads();

    int row = blockIdx.x * 256 + tid;
    if (row >= RROWS) return;

    const float* xr = in + (size_t)row * CDIM;
    float x[CDIM];
#pragma unroll
    for (int k = 0; k < CDIM / 4; ++k) {
        float4 v = ((const float4*)xr)[k];
        x[4 * k + 0] = v.x; x[4 * k + 1] = v.y;
        x[4 * k + 2] = v.z; x[4 * k + 3] = v.w;
    }

    float hr[CDIM];
#pragma unroll
    for (int c = 0; c < CDIM; ++c) {
        float acc = 0.f;
#pragma unroll
        for (int k = 0; k < CDIM; ++k) acc += x[k] * sW[k][c];
        hr[c] = acc;
    }

    float* hrow = h + (size_t)row * CDIM;
#pragma unroll
    for (int k = 0; k < CDIM / 4; ++k) {
        ((float4*)hrow)[k] = make_float4(hr[4 * k], hr[4 * k + 1],
                                         hr[4 * k + 2], hr[4 * k + 3]);
    }

#pragma unroll
    for (int c = 0; c < CDIM; ++c) {
        float acc = 0.f;
#pragma unroll
        for (int k = 0; k < CDIM; ++k) acc += hr[k] * sU[k][c];
        x[c] = acc;
    }

    float* hurow = hu + (size_t)row * CDIM;
#pragma unroll
    for (int k = 0; k < CDIM / 4; ++k) {
        ((float4*)hurow)[k] = make_float4(x[4 * k], x[4 * k + 1],
                                          x[4 * k + 2], x[4 * k + 3]);
    }
}

// ---------------------------------------------------------------------------
// CSR build: hist -> 3-stage parallel scan -> scatter.  Once per launch.
// ---------------------------------------------------------------------------
__global__ __launch_bounds__(256) void zero_counts_kernel(int* __restrict__ counts)
{
    int i = blockIdx.x * 256 + threadIdx.x;
    if (i < NNODES) counts[i] = 0;
}

__global__ __launch_bounds__(256) void hist_kernel(
    const int* __restrict__ ei, int* __restrict__ counts)
{
    int e = blockIdx.x * 256 + threadIdx.x;
    if (e < NEDGES) atomicAdd(&counts[ei[NEDGES + e]], 1);
}

// per-block sums of counts (79 blocks x 256)
__global__ __launch_bounds__(256) void blocksum_kernel(
    const int* __restrict__ counts, int* __restrict__ bsum)
{
    __shared__ int sd[256];
    int tid = threadIdx.x;
    int i = blockIdx.x * 256 + tid;
    sd[tid] = (i < NNODES) ? counts[i] : 0;
    __syncthreads();
#pragma unroll
    for (int off = 128; off > 0; off >>= 1) {
        if (tid < off) sd[tid] += sd[tid + off];
        __syncthreads();
    }
    if (tid == 0) bsum[blockIdx.x] = sd[0];
}

// exclusive scan of the 79 block sums (1 block, 128 threads)
__global__ __launch_bounds__(128) void bscan_kernel(
    const int* __restrict__ bsum, int* __restrict__ bbase, int nblocks)
{
    __shared__ int sd[128];
    int tid = threadIdx.x;
    int v = (tid < nblocks) ? bsum[tid] : 0;
    sd[tid] = v;
    __syncthreads();
#pragma unroll
    for (int off = 1; off < 128; off <<= 1) {
        int t = (tid >= off) ? sd[tid - off] : 0;
        __syncthreads();
        sd[tid] += t;
        __syncthreads();
    }
    if (tid < nblocks) bbase[tid] = sd[tid] - v;   // exclusive
}

// local exclusive scan + add block base -> offsets, cursor
__global__ __launch_bounds__(256) void localscan_kernel(
    const int* __restrict__ counts, const int* __restrict__ bbase,
    int* __restrict__ offsets, int* __restrict__ cursor)
{
    __shared__ int sd[256];
    int tid = threadIdx.x;
    int i = blockIdx.x * 256 + tid;
    int v = (i < NNODES) ? counts[i] : 0;
    sd[tid] = v;
    __syncthreads();
#pragma unroll
    for (int off = 1; off < 256; off <<= 1) {
        int t = (tid >= off) ? sd[tid - off] : 0;
        __syncthreads();
        sd[tid] += t;
        __syncthreads();
    }
    int excl = bbase[blockIdx.x] + sd[tid] - v;
    if (i < NNODES) { offsets[i] = excl; cursor[i] = excl; }
    if (i == NNODES - 1) offsets[NNODES] = NEDGES;
}

__global__ __launch_bounds__(256) void scatter_kernel(
    const int* __restrict__ ei,
    int* __restrict__ cursor,
    int* __restrict__ csr_src)
{
    int e = blockIdx.x * 256 + threadIdx.x;
    if (e < NEDGES) {
        int t = ei[NEDGES + e];
        int pos = atomicAdd(&cursor[t], 1);
        csr_src[pos] = ei[e];
    }
}

// ---------------------------------------------------------------------------
// Aggregation kernel: one block per target node.
// Geometry: 256 thr = 4 waves (edge slots) x 8 tau x 8 lanes x 4 channels.
// Per (edge,tau): 8 lanes, dot = 4 FMA + 3-step shfl butterfly (was 32 lanes /
// 5 steps).  A wave's 64 lanes read one full 1KB src-node row -> one fully
// coalesced gather per edge.  Slot maxes combined via LDS.  Unroll-2 for ILP.
// Writes out = leaky_relu(h + agg, 0.01) once.  `h`/`out` may alias.
// ---------------------------------------------------------------------------
__global__ __launch_bounds__(256) void agg_kernel(
    const int* __restrict__ offsets,
    const int* __restrict__ csr_src,
    const float* __restrict__ hu,   // gather source [RROWS,32]
    const float* h,                 // [RROWS,32]
    float* out)                     // [RROWS,32]
{
    __shared__ float4 sm[256];
    int n = blockIdx.x;
    int tid = threadIdx.x;
    int slot = tid >> 6;                 // wave id 0..3 = edge slot
    int l64  = tid & 63;                 // tau*8 + li
    size_t nodeBase = (size_t)n * ROWBLK;
    size_t rowOff = (size_t)l64 * 4;     // tau*32 + li*4

    float4 bv = *(const float4*)(hu + nodeBase + rowOff);   // x_i quad

    int k0 = offsets[n];
    int k1 = offsets[n + 1];

    float4 m = make_float4(-INFINITY, -INFINITY, -INFINITY, -INFINITY);

    int k = k0 + slot;
    // unroll-2: two edges (k, k+4) in flight per wave
    for (; k + 4 < k1; k += 8) {
        int s0 = csr_src[k];
        int s1 = csr_src[k + 4];
        float4 a0 = *(const float4*)(hu + (size_t)s0 * ROWBLK + rowOff);
        float4 a1 = *(const float4*)(hu + (size_t)s1 * ROWBLK + rowOff);
        float p0 = a0.x * bv.x + a0.y * bv.y + a0.z * bv.z + a0.w * bv.w;
        float p1 = a1.x * bv.x + a1.y * bv.y + a1.z * bv.z + a1.w * bv.w;
        p0 += __shfl_xor(p0, 1);  p1 += __shfl_xor(p1, 1);
        p0 += __shfl_xor(p0, 2);  p1 += __shfl_xor(p1, 2);
        p0 += __shfl_xor(p0, 4);  p1 += __shfl_xor(p1, 4);
        float g0 = 1.f / (1.f + __expf(-p0));
        float g1 = 1.f / (1.f + __expf(-p1));
        m = fmax4(m, make_float4(a0.x * g0, a0.y * g0, a0.z * g0, a0.w * g0));
        m = fmax4(m, make_float4(a1.x * g1, a1.y * g1, a1.z * g1, a1.w * g1));
    }
    if (k < k1) {
        int s0 = csr_src[k];
        float4 a0 = *(const float4*)(hu + (size_t)s0 * ROWBLK + rowOff);
        float p0 = a0.x * bv.x + a0.y * bv.y + a0.z * bv.z + a0.w * bv.w;
        p0 += __shfl_xor(p0, 1);
        p0 += __shfl_xor(p0, 2);
        p0 += __shfl_xor(p0, 4);
        float g0 = 1.f / (1.f + __expf(-p0));
        m = fmax4(m, make_float4(a0.x * g0, a0.y * g0, a0.z * g0, a0.w * g0));
    }

    sm[tid] = m;
    __syncthreads();

    if (tid < 64) {
        float4 m0 = sm[tid];
        float4 m1 = sm[tid + 64];
        float4 m2 = sm[tid + 128];
        float4 m3 = sm[tid + 192];
        float4 mm = fmax4(fmax4(m0, m1), fmax4(m2, m3));
        bool has = (k1 > k0);
        size_t base = nodeBase + (size_t)tid * 4;
        float4 hv = *(const float4*)(h + base);
        float4 o;
        float ax = has ? mm.x : 0.f;
        float ay = has ? mm.y : 0.f;
        float az = has ? mm.z : 0.f;
        float aw = has ? mm.w : 0.f;
        float vx = hv.x + ax, vy = hv.y + ay, vz = hv.z + az, vw = hv.w + aw;
        o.x = (vx >= 0.f) ? vx : 0.01f * vx;
        o.y = (vy >= 0.f) ? vy : 0.01f * vy;
        o.z = (vz >= 0.f) ? vz : 0.01f * vz;
        o.w = (vw >= 0.f) ? vw : 0.01f * vw;
        *(float4*)(out + base) = o;
    }
}

// ---------------------------------------------------------------------------
// Orchestration.
// ws: [counts N][offsets N+1][cursor N][bsum 128][bbase 128][csr E][pad][A NELEM]
// Layer 1: linear2(X)->h1=A, hu1=d_out;  agg(hu=d_out,h=A)->c1=A (in place)
// Layer 2: linear2(A)->h2=d_out, hu2=A (in place); agg(hu=A,h=d_out)->d_out
// ---------------------------------------------------------------------------
extern "C" void kernel_launch(void* const* d_in, const int* in_sizes, int n_in,
                              void* d_out, int out_size, void* d_ws, size_t ws_size,
                              hipStream_t stream)
{
    const float* X   = (const float*)d_in[0];
    const int*   ei  = (const int*)  d_in[1];
    // d_in[2]=edge_attr, d_in[4]=We1, d_in[7]=We2: dead code in reference
    const float* Wn1 = (const float*)d_in[3];
    const float* u1  = (const float*)d_in[5];
    const float* Wn2 = (const float*)d_in[6];
    const float* u2  = (const float*)d_in[8];

    float* out = (float*)d_out;

    int* counts  = (int*)d_ws;
    int* offsets = counts + NNODES;          // NNODES+1
    int* cursor  = offsets + NNODES + 1;
    int* bsum    = cursor + NNODES;          // 128
    int* bbase   = bsum + 128;               // 128
    int* csr     = bbase + 128;              // NEDGES
    float* A = (float*)(((uintptr_t)(csr + NEDGES) + 255) & ~(uintptr_t)255);

    const int rowBlocks  = (RROWS + 255) / 256;    // 625
    const int edgeBlocks = (NEDGES + 255) / 256;   // 1250
    const int nodeBlocks = (NNODES + 255) / 256;   // 79

    // ---- CSR build (shared by both layers) ----
    zero_counts_kernel<<<nodeBlocks, 256, 0, stream>>>(counts);
    hist_kernel<<<edgeBlocks, 256, 0, stream>>>(ei, counts);
    blocksum_kernel<<<nodeBlocks, 256, 0, stream>>>(counts, bsum);
    bscan_kernel<<<1, 128, 0, stream>>>(bsum, bbase, nodeBlocks);
    localscan_kernel<<<nodeBlocks, 256, 0, stream>>>(counts, bbase, offsets, cursor);
    scatter_kernel<<<edgeBlocks, 256, 0, stream>>>(ei, cursor, csr);

    // ---- layer 1 ----
    linear2_kernel<<<rowBlocks, 256, 0, stream>>>(X, Wn1, u1, A, out);
    agg_kernel<<<NNODES, 256, 0, stream>>>(offsets, csr, out, A, A);

    // ---- layer 2 ----
    linear2_kernel<<<rowBlocks, 256, 0, stream>>>(A, Wn2, u2, out, A);
    agg_kernel<<<NNODES, 256, 0, stream>>>(offsets, csr, A, out, out);
}